// Round 20
// baseline (202.582 us; speedup 1.0000x reference)
//
#include <hip/hip_runtime.h>
#include <hip/hip_bf16.h>

// SO3Conv restructured (journal R7-R19):
//   PT_l[(yo,v)][(x,u)] = psi_l scaled, bf16 ; A_l[(b,i)][(x,u)] = x, bf16
//   Y_l = A_l . PT_l^T  via mfma_f32_16x16x32_bf16
// l=0..5, d=2l+1, off_l = {0,1,10,35,84,165}.
// R20: main_gemm keeps A in dbuf LDS (4-way shared) but reads B fragments
// DIRECTLY global->VGPR (B was only 2-way shared, same-CU -> L1 covers it).
// Halves per-barrier drain volume + LDS footprint (32KB -> 4-5 blocks/CU).

#define NT 256
typedef __bf16 bf16x8 __attribute__((ext_vector_type(8)));
typedef float f32x4 __attribute__((ext_vector_type(4)));
typedef unsigned int u32;

__device__ __forceinline__ void gload_lds16(const void* g, void* l) {
  __builtin_amdgcn_global_load_lds(
      (const __attribute__((address_space(1))) u32*)g,
      (__attribute__((address_space(3))) u32*)l, 16, 0, 0);
}

__device__ __forceinline__ void decode_s(int s, int& off, int& d) {
  if (s >= 165)      { off = 165; d = 11; }
  else if (s >= 84)  { off = 84;  d = 9; }
  else if (s >= 35)  { off = 35;  d = 7; }
  else if (s >= 10)  { off = 10;  d = 5; }
  else if (s >= 1)   { off = 1;   d = 3; }
  else               { off = 0;   d = 1; }
}

// ---------------------------------------------------------------------------
// Kernel 0: prep_all (7936 blocks): wb=bf16(w); DT=bf16(D^T) padded; build_A.
// ---------------------------------------------------------------------------
template<int D, int OFF>
__device__ __forceinline__ void build_one(const float* __restrict__ X,
                                          __hip_bfloat16* __restrict__ A,
                                          int b, __hip_bfloat16* sm) {
  const float* src = X + (size_t)b * (128 * 286) + OFF;
  for (int e = threadIdx.x; e < 128 * D * D; e += NT) {
    const int x = e / (D * D), r = e - x * (D * D);
    sm[e] = __float2bfloat16(src[x * 286 + r]);
  }
  __syncthreads();
  __hip_bfloat16* dst = A + (size_t)65536 * OFF + (size_t)b * (D * 128 * D);
  for (int o = threadIdx.x; o < D * 128 * D; o += NT) {
    const int i = o / (128 * D);
    const int rem = o - i * (128 * D);
    const int x = rem / D, u = rem - x * D;
    dst[o] = sm[x * D * D + u * D + i];
  }
}

__global__ __launch_bounds__(NT)
void prep_all(const float* __restrict__ w, const float* __restrict__ Dm,
              const float* __restrict__ X,
              __hip_bfloat16* __restrict__ wb, __hip_bfloat16* __restrict__ DT,
              __hip_bfloat16* __restrict__ A) {
  __shared__ __hip_bfloat16 sm[128 * 121];
  const int bx = blockIdx.x;
  if (bx < 4096) {
    const int t = bx * NT + threadIdx.x;
    const float4 a = reinterpret_cast<const float4*>(w)[t * 2];
    const float4 b = reinterpret_cast<const float4*>(w)[t * 2 + 1];
    __hip_bfloat16 v[8];
    v[0] = __float2bfloat16(a.x); v[1] = __float2bfloat16(a.y);
    v[2] = __float2bfloat16(a.z); v[3] = __float2bfloat16(a.w);
    v[4] = __float2bfloat16(b.x); v[5] = __float2bfloat16(b.y);
    v[6] = __float2bfloat16(b.z); v[7] = __float2bfloat16(b.w);
    *reinterpret_cast<bf16x8*>(&wb[t * 8]) = *reinterpret_cast<bf16x8*>(v);
  } else if (bx < 4864) {
    const int e = (bx - 4096) * NT + threadIdx.x;  // 196,608 = 384*512
    const int s = e >> 9, g = e & 511;
    DT[e] = (s < 286) ? __float2bfloat16(Dm[g * 286 + s]) : __float2bfloat16(0.0f);
  } else {
    const int b2 = bx - 4864;
    if (b2 < 512)       build_one<11, 165>(X, A, b2, sm);
    else if (b2 < 1024) build_one<9, 84>(X, A, b2 - 512, sm);
    else if (b2 < 1536) build_one<7, 35>(X, A, b2 - 1024, sm);
    else if (b2 < 2048) build_one<5, 10>(X, A, b2 - 1536, sm);
    else if (b2 < 2560) build_one<3, 1>(X, A, b2 - 2048, sm);
    else                build_one<1, 0>(X, A, b2 - 2560, sm);
  }
}

// ---------------------------------------------------------------------------
// Shared helpers.
// ---------------------------------------------------------------------------
__device__ __forceinline__ void stage_tile(
    const __hip_bfloat16* __restrict__ Ap, const __hip_bfloat16* __restrict__ Bp,
    int LDK, int ktv, int m0, int n0, int tid, int wave,
    __hip_bfloat16* sA, __hip_bfloat16* sB) {
#pragma unroll
  for (int c = 0; c < 4; ++c) {
    const int q = c * 256 + tid;
    const int row = q >> 3, slot = q & 7;
    const int scol = ((slot ^ (row & 7)) << 3);
    gload_lds16(&Ap[(m0 + row) * LDK + ktv + scol], &sA[(c * 256 + wave * 64) << 3]);
    gload_lds16(&Bp[(n0 + row) * LDK + ktv + scol], &sB[(c * 256 + wave * 64) << 3]);
  }
}

// A-only staging (16 KB per K-step, 4 gload_lds/thread)
__device__ __forceinline__ void stage_A(
    const __hip_bfloat16* __restrict__ Ap, int LDK, int ktv, int m0,
    int tid, int wave, __hip_bfloat16* sA) {
#pragma unroll
  for (int c = 0; c < 4; ++c) {
    const int q = c * 256 + tid;
    const int row = q >> 3, slot = q & 7;
    const int scol = ((slot ^ (row & 7)) << 3);
    gload_lds16(&Ap[(m0 + row) * LDK + ktv + scol], &sA[(c * 256 + wave * 64) << 3]);
  }
}

__device__ __forceinline__ void load_frags(
    const __hip_bfloat16* sA, const __hip_bfloat16* sB,
    int wr, int wc, int r15, int khi, bf16x8 (&af)[4][2], bf16x8 (&bf)[4][2]) {
#pragma unroll
  for (int m = 0; m < 4; ++m)
#pragma unroll
    for (int kk = 0; kk < 2; ++kk) {
      const int row = wr * 64 + m * 16 + r15;
      const int slot = (kk * 4 + khi) ^ (row & 7);
      af[m][kk] = *reinterpret_cast<const bf16x8*>(&sA[row * 64 + slot * 8]);
    }
#pragma unroll
  for (int n = 0; n < 4; ++n)
#pragma unroll
    for (int kk = 0; kk < 2; ++kk) {
      const int row = wc * 64 + n * 16 + r15;
      const int slot = (kk * 4 + khi) ^ (row & 7);
      bf[n][kk] = *reinterpret_cast<const bf16x8*>(&sB[row * 64 + slot * 8]);
    }
}

// A fragments from LDS (swizzled, as before)
__device__ __forceinline__ void load_afrags(
    const __hip_bfloat16* sA, int wr, int r15, int khi, bf16x8 (&af)[4][2]) {
#pragma unroll
  for (int m = 0; m < 4; ++m)
#pragma unroll
    for (int kk = 0; kk < 2; ++kk) {
      const int row = wr * 64 + m * 16 + r15;
      const int slot = (kk * 4 + khi) ^ (row & 7);
      af[m][kk] = *reinterpret_cast<const bf16x8*>(&sA[row * 64 + slot * 8]);
    }
}

// B fragments DIRECT from global (bit-identical values to the LDS path)
__device__ __forceinline__ void load_bdir(
    const __hip_bfloat16* __restrict__ BT, int LDK, int ktv, int n0,
    int wc, int r15, int khi, bf16x8 (&bf)[4][2]) {
#pragma unroll
  for (int n = 0; n < 4; ++n)
#pragma unroll
    for (int kk = 0; kk < 2; ++kk) {
      const int row = n0 + wc * 64 + n * 16 + r15;
      bf[n][kk] = *reinterpret_cast<const bf16x8*>(
          &BT[row * LDK + ktv + ((kk * 4 + khi) << 3)]);
    }
}

__device__ __forceinline__ void do_mfma(
    const bf16x8 (&af)[4][2], const bf16x8 (&bf)[4][2], f32x4 (&acc)[4][4]) {
#pragma unroll
  for (int kk = 0; kk < 2; ++kk)
#pragma unroll
    for (int m = 0; m < 4; ++m)
#pragma unroll
      for (int n = 0; n < 4; ++n)
        acc[m][n] = __builtin_amdgcn_mfma_f32_16x16x32_bf16(
            af[m][kk], bf[n][kk], acc[m][n], 0, 0, 0);
}

// ---------------------------------------------------------------------------
// Kernel 1: psi MFMA GEMM (unchanged, proven).
// ---------------------------------------------------------------------------
__global__ __launch_bounds__(NT)
void psi_mfma(const __hip_bfloat16* __restrict__ wb,
              const __hip_bfloat16* __restrict__ DT,
              __hip_bfloat16* __restrict__ PT) {
  const int m0 = blockIdx.x * 128, n0 = blockIdx.y * 128;

  __shared__ __hip_bfloat16 sA[2][128 * 64];
  __shared__ __hip_bfloat16 sB[2][128 * 64];

  const int tid = threadIdx.x;
  const int lane = tid & 63, wave = tid >> 6;
  const int wr = wave & 1, wc = wave >> 1;
  const int r15 = lane & 15, khi = lane >> 4;

  f32x4 acc[4][4] = {};
  bf16x8 af[4][2], bf[4][2];

  stage_tile(wb, DT, 512, 0, m0, n0, tid, wave, sA[0], sB[0]);
  __syncthreads();
  int cur = 0;
  for (int t = 0; t < 8; ++t) {
    if (t + 1 < 8)
      stage_tile(wb, DT, 512, (t + 1) << 6, m0, n0, tid, wave, sA[cur ^ 1], sB[cur ^ 1]);
    load_frags(sA[cur], sB[cur], wr, wc, r15, khi, af, bf);
    do_mfma(af, bf, acc);
    if (t + 1 < 8) { __syncthreads(); cur ^= 1; }
  }

#pragma unroll
  for (int n = 0; n < 4; ++n) {
    const int s = n0 + wc * 64 + n * 16 + r15;
    if (s >= 286) continue;
    int off, d;
    decode_s(s, off, d);
    const int rel = s - off;
    const int u = rel / d, v = rel - u * d;
    const float scale = 1.0f / (256.0f * sqrtf((float)d));
    __hip_bfloat16* Pl = PT + off * 16384;
    const int Kd = 128 * d;
#pragma unroll
    for (int m = 0; m < 4; ++m)
#pragma unroll
      for (int j = 0; j < 4; ++j) {
        const int row = m0 + wr * 64 + m * 16 + khi * 4 + j;
        const int x = row >> 7, y = row & 127;
        Pl[(y * d + v) * Kd + (x * d + u)] = __float2bfloat16(acc[m][n][j] * scale);
      }
  }
}

// ---------------------------------------------------------------------------
// Kernel 2: main GEMM — A dbuf-LDS (R8 cadence), B direct-to-register.
// LDS 32 KB -> 4-5 blocks/CU. 1144 blocks, longest degree first.
// ---------------------------------------------------------------------------
__global__ __launch_bounds__(NT)
void main_gemm(const __hip_bfloat16* __restrict__ Aall,
               const __hip_bfloat16* __restrict__ PTall,
               float* __restrict__ out) {
  int bx = blockIdx.x;
  int off, d;
  if (bx < 484)       { off = 165; d = 11; }
  else if (bx < 808)  { off = 84;  d = 9;  bx -= 484; }
  else if (bx < 1004) { off = 35;  d = 7;  bx -= 808; }
  else if (bx < 1104) { off = 10;  d = 5;  bx -= 1004; }
  else if (bx < 1140) { off = 1;   d = 3;  bx -= 1104; }
  else                { off = 0;   d = 1;  bx -= 1140; }
  const int bm = bx % (4 * d);
  const int bn = bx / (4 * d);
  const int Kn = 128 * d;
  const __hip_bfloat16* A  = Aall  + 65536 * off;
  const __hip_bfloat16* BT = PTall + 16384 * off;
  const int m0 = bm * 128, n0 = bn * 128;

  __shared__ __hip_bfloat16 sA[2][128 * 64];   // 32 KB total

  const int tid = threadIdx.x;
  const int lane = tid & 63, wave = tid >> 6;
  const int wr = wave & 1, wc = wave >> 1;
  const int r15 = lane & 15, khi = lane >> 4;

  f32x4 acc[4][4] = {};
  bf16x8 af[4][2], bf[4][2];

  const int nk = Kn >> 6;
  stage_A(A, Kn, 0, m0, tid, wave, sA[0]);
  __syncthreads();
  int cur = 0;
  for (int t = 0; t < nk; ++t) {
    if (t + 1 < nk)
      stage_A(A, Kn, (t + 1) << 6, m0, tid, wave, sA[cur ^ 1]);
    load_bdir(BT, Kn, t << 6, n0, wc, r15, khi, bf);
    load_afrags(sA[cur], wr, r15, khi, af);
    do_mfma(af, bf, acc);
    if (t + 1 < nk) { __syncthreads(); cur ^= 1; }
  }

  // Epilogue: row m=(b,i), col n=(yo,v) -> out[b][yo][off + v*d + i]
  int yo4[4], v4[4];
#pragma unroll
  for (int n = 0; n < 4; ++n) {
    const int col = n0 + wc * 64 + n * 16 + r15;
    yo4[n] = col / d;
    v4[n] = col - yo4[n] * d;
  }
#pragma unroll
  for (int m = 0; m < 4; ++m)
#pragma unroll
    for (int j = 0; j < 4; ++j) {
      const int row = m0 + wr * 64 + m * 16 + khi * 4 + j;
      const int bb = row / d, i = row - bb * d;
      float* orow = out + (size_t)bb * 36608 + off + i;
#pragma unroll
      for (int n = 0; n < 4; ++n)
        orow[yo4[n] * 286 + v4[n] * d] = acc[m][n][j];
    }
}

// ---------------------------------------------------------------------------
extern "C" void kernel_launch(void* const* d_in, const int* in_sizes, int n_in,
                              void* d_out, int out_size, void* d_ws, size_t ws_size,
                              hipStream_t stream) {
  const float* x  = (const float*)d_in[0];  // (512,128,286)
  const float* w  = (const float*)d_in[1];  // (128,128,512)
  const float* Dm = (const float*)d_in[2];  // (512,286)
  float* out = (float*)d_out;               // (512,128,286)

  // Workspace (bf16 elems): PT 16384*286 ; A 65536*286 ; wb 16384*512 ;
  // DT 384*512.
  __hip_bfloat16* PT = (__hip_bfloat16*)d_ws;
  __hip_bfloat16* A  = PT + 16384 * 286;
  __hip_bfloat16* wb = A + 65536 * 286;
  __hip_bfloat16* DT = wb + 16384 * 512;

  prep_all<<<dim3(7936), dim3(NT), 0, stream>>>(w, Dm, x, wb, DT, A);
  psi_mfma<<<dim3(128, 3), dim3(NT), 0, stream>>>(wb, DT, PT);
  main_gemm<<<dim3(1144), dim3(NT), 0, stream>>>(A, PT, out);
}

// Round 21
// 161.585 us; speedup vs baseline: 1.2537x; 1.2537x over previous
//
#include <hip/hip_runtime.h>
#include <hip/hip_bf16.h>

// SO3Conv restructured (journal R7-R20):
//   PT_l[(yo,v)][(x,u)] = psi_l scaled, bf16 ; A_l[(b,i)][(x,u)] = x, bf16
//   Y_l = A_l . PT_l^T  via mfma_f32_16x16x32_bf16
// l=0..5, d=2l+1, off_l = {0,1,10,35,84,165}.
// R21 = R18/R19 verbatim (twice-verified best: 161-163us total; main
// 108us/VGPR 88/FETCH 80MB). 13 structural variants measured; 2-phase-family
// optimum. R20's B-direct (-36us) refuted the last untested axis.

#define NT 256
typedef __bf16 bf16x8 __attribute__((ext_vector_type(8)));
typedef float f32x4 __attribute__((ext_vector_type(4)));
typedef unsigned int u32;

__device__ __forceinline__ void gload_lds16(const void* g, void* l) {
  __builtin_amdgcn_global_load_lds(
      (const __attribute__((address_space(1))) u32*)g,
      (__attribute__((address_space(3))) u32*)l, 16, 0, 0);
}

__device__ __forceinline__ void decode_s(int s, int& off, int& d) {
  if (s >= 165)      { off = 165; d = 11; }
  else if (s >= 84)  { off = 84;  d = 9; }
  else if (s >= 35)  { off = 35;  d = 7; }
  else if (s >= 10)  { off = 10;  d = 5; }
  else if (s >= 1)   { off = 1;   d = 3; }
  else               { off = 0;   d = 1; }
}

// ---------------------------------------------------------------------------
// Kernel 0: prep_all (7936 blocks): wb=bf16(w); DT=bf16(D^T) padded; build_A.
// ---------------------------------------------------------------------------
template<int D, int OFF>
__device__ __forceinline__ void build_one(const float* __restrict__ X,
                                          __hip_bfloat16* __restrict__ A,
                                          int b, __hip_bfloat16* sm) {
  const float* src = X + (size_t)b * (128 * 286) + OFF;
  for (int e = threadIdx.x; e < 128 * D * D; e += NT) {
    const int x = e / (D * D), r = e - x * (D * D);
    sm[e] = __float2bfloat16(src[x * 286 + r]);
  }
  __syncthreads();
  __hip_bfloat16* dst = A + (size_t)65536 * OFF + (size_t)b * (D * 128 * D);
  for (int o = threadIdx.x; o < D * 128 * D; o += NT) {
    const int i = o / (128 * D);
    const int rem = o - i * (128 * D);
    const int x = rem / D, u = rem - x * D;
    dst[o] = sm[x * D * D + u * D + i];
  }
}

__global__ __launch_bounds__(NT)
void prep_all(const float* __restrict__ w, const float* __restrict__ Dm,
              const float* __restrict__ X,
              __hip_bfloat16* __restrict__ wb, __hip_bfloat16* __restrict__ DT,
              __hip_bfloat16* __restrict__ A) {
  __shared__ __hip_bfloat16 sm[128 * 121];
  const int bx = blockIdx.x;
  if (bx < 4096) {
    const int t = bx * NT + threadIdx.x;
    const float4 a = reinterpret_cast<const float4*>(w)[t * 2];
    const float4 b = reinterpret_cast<const float4*>(w)[t * 2 + 1];
    __hip_bfloat16 v[8];
    v[0] = __float2bfloat16(a.x); v[1] = __float2bfloat16(a.y);
    v[2] = __float2bfloat16(a.z); v[3] = __float2bfloat16(a.w);
    v[4] = __float2bfloat16(b.x); v[5] = __float2bfloat16(b.y);
    v[6] = __float2bfloat16(b.z); v[7] = __float2bfloat16(b.w);
    *reinterpret_cast<bf16x8*>(&wb[t * 8]) = *reinterpret_cast<bf16x8*>(v);
  } else if (bx < 4864) {
    const int e = (bx - 4096) * NT + threadIdx.x;  // 196,608 = 384*512
    const int s = e >> 9, g = e & 511;
    DT[e] = (s < 286) ? __float2bfloat16(Dm[g * 286 + s]) : __float2bfloat16(0.0f);
  } else {
    const int b2 = bx - 4864;
    if (b2 < 512)       build_one<11, 165>(X, A, b2, sm);
    else if (b2 < 1024) build_one<9, 84>(X, A, b2 - 512, sm);
    else if (b2 < 1536) build_one<7, 35>(X, A, b2 - 1024, sm);
    else if (b2 < 2048) build_one<5, 10>(X, A, b2 - 1536, sm);
    else if (b2 < 2560) build_one<3, 1>(X, A, b2 - 2048, sm);
    else                build_one<1, 0>(X, A, b2 - 2560, sm);
  }
}

// ---------------------------------------------------------------------------
// Shared helpers (proven R7/R8 structure).
// ---------------------------------------------------------------------------
__device__ __forceinline__ void stage_tile(
    const __hip_bfloat16* __restrict__ Ap, const __hip_bfloat16* __restrict__ Bp,
    int LDK, int ktv, int m0, int n0, int tid, int wave,
    __hip_bfloat16* sA, __hip_bfloat16* sB) {
#pragma unroll
  for (int c = 0; c < 4; ++c) {
    const int q = c * 256 + tid;
    const int row = q >> 3, slot = q & 7;
    const int scol = ((slot ^ (row & 7)) << 3);
    gload_lds16(&Ap[(m0 + row) * LDK + ktv + scol], &sA[(c * 256 + wave * 64) << 3]);
    gload_lds16(&Bp[(n0 + row) * LDK + ktv + scol], &sB[(c * 256 + wave * 64) << 3]);
  }
}

__device__ __forceinline__ void load_frags(
    const __hip_bfloat16* sA, const __hip_bfloat16* sB,
    int wr, int wc, int r15, int khi, bf16x8 (&af)[4][2], bf16x8 (&bf)[4][2]) {
#pragma unroll
  for (int m = 0; m < 4; ++m)
#pragma unroll
    for (int kk = 0; kk < 2; ++kk) {
      const int row = wr * 64 + m * 16 + r15;
      const int slot = (kk * 4 + khi) ^ (row & 7);
      af[m][kk] = *reinterpret_cast<const bf16x8*>(&sA[row * 64 + slot * 8]);
    }
#pragma unroll
  for (int n = 0; n < 4; ++n)
#pragma unroll
    for (int kk = 0; kk < 2; ++kk) {
      const int row = wc * 64 + n * 16 + r15;
      const int slot = (kk * 4 + khi) ^ (row & 7);
      bf[n][kk] = *reinterpret_cast<const bf16x8*>(&sB[row * 64 + slot * 8]);
    }
}

__device__ __forceinline__ void do_mfma(
    const bf16x8 (&af)[4][2], const bf16x8 (&bf)[4][2], f32x4 (&acc)[4][4]) {
#pragma unroll
  for (int kk = 0; kk < 2; ++kk)
#pragma unroll
    for (int m = 0; m < 4; ++m)
#pragma unroll
      for (int n = 0; n < 4; ++n)
        acc[m][n] = __builtin_amdgcn_mfma_f32_16x16x32_bf16(
            af[m][kk], bf[n][kk], acc[m][n], 0, 0, 0);
}

// ---------------------------------------------------------------------------
// Kernel 1: psi MFMA GEMM (unchanged, proven).
// ---------------------------------------------------------------------------
__global__ __launch_bounds__(NT)
void psi_mfma(const __hip_bfloat16* __restrict__ wb,
              const __hip_bfloat16* __restrict__ DT,
              __hip_bfloat16* __restrict__ PT) {
  const int m0 = blockIdx.x * 128, n0 = blockIdx.y * 128;

  __shared__ __hip_bfloat16 sA[2][128 * 64];
  __shared__ __hip_bfloat16 sB[2][128 * 64];

  const int tid = threadIdx.x;
  const int lane = tid & 63, wave = tid >> 6;
  const int wr = wave & 1, wc = wave >> 1;
  const int r15 = lane & 15, khi = lane >> 4;

  f32x4 acc[4][4] = {};
  bf16x8 af[4][2], bf[4][2];

  stage_tile(wb, DT, 512, 0, m0, n0, tid, wave, sA[0], sB[0]);
  __syncthreads();
  int cur = 0;
  for (int t = 0; t < 8; ++t) {
    if (t + 1 < 8)
      stage_tile(wb, DT, 512, (t + 1) << 6, m0, n0, tid, wave, sA[cur ^ 1], sB[cur ^ 1]);
    load_frags(sA[cur], sB[cur], wr, wc, r15, khi, af, bf);
    do_mfma(af, bf, acc);
    if (t + 1 < 8) { __syncthreads(); cur ^= 1; }
  }

#pragma unroll
  for (int n = 0; n < 4; ++n) {
    const int s = n0 + wc * 64 + n * 16 + r15;
    if (s >= 286) continue;
    int off, d;
    decode_s(s, off, d);
    const int rel = s - off;
    const int u = rel / d, v = rel - u * d;
    const float scale = 1.0f / (256.0f * sqrtf((float)d));
    __hip_bfloat16* Pl = PT + off * 16384;
    const int Kd = 128 * d;
#pragma unroll
    for (int m = 0; m < 4; ++m)
#pragma unroll
      for (int j = 0; j < 4; ++j) {
        const int row = m0 + wr * 64 + m * 16 + khi * 4 + j;
        const int x = row >> 7, y = row & 127;
        Pl[(y * d + v) * Kd + (x * d + u)] = __float2bfloat16(acc[m][n][j] * scale);
      }
  }
}

// ---------------------------------------------------------------------------
// Kernel 2: main GEMM — exact R8 structure (runtime-d, dbuf, VGPR-lean).
// 1144 blocks, longest degree first. No swizzle, no extra launch bounds.
// ---------------------------------------------------------------------------
__global__ __launch_bounds__(NT)
void main_gemm(const __hip_bfloat16* __restrict__ Aall,
               const __hip_bfloat16* __restrict__ PTall,
               float* __restrict__ out) {
  int bx = blockIdx.x;
  int off, d;
  if (bx < 484)       { off = 165; d = 11; }
  else if (bx < 808)  { off = 84;  d = 9;  bx -= 484; }
  else if (bx < 1004) { off = 35;  d = 7;  bx -= 808; }
  else if (bx < 1104) { off = 10;  d = 5;  bx -= 1004; }
  else if (bx < 1140) { off = 1;   d = 3;  bx -= 1104; }
  else                { off = 0;   d = 1;  bx -= 1140; }
  const int bm = bx % (4 * d);
  const int bn = bx / (4 * d);
  const int Kn = 128 * d;
  const __hip_bfloat16* A  = Aall  + 65536 * off;
  const __hip_bfloat16* BT = PTall + 16384 * off;
  const int m0 = bm * 128, n0 = bn * 128;

  __shared__ __hip_bfloat16 sA[2][128 * 64];
  __shared__ __hip_bfloat16 sB[2][128 * 64];

  const int tid = threadIdx.x;
  const int lane = tid & 63, wave = tid >> 6;
  const int wr = wave & 1, wc = wave >> 1;
  const int r15 = lane & 15, khi = lane >> 4;

  f32x4 acc[4][4] = {};
  bf16x8 af[4][2], bf[4][2];

  const int nk = Kn >> 6;
  stage_tile(A, BT, Kn, 0, m0, n0, tid, wave, sA[0], sB[0]);
  __syncthreads();
  int cur = 0;
  for (int t = 0; t < nk; ++t) {
    if (t + 1 < nk)
      stage_tile(A, BT, Kn, (t + 1) << 6, m0, n0, tid, wave, sA[cur ^ 1], sB[cur ^ 1]);
    load_frags(sA[cur], sB[cur], wr, wc, r15, khi, af, bf);
    do_mfma(af, bf, acc);
    if (t + 1 < nk) { __syncthreads(); cur ^= 1; }
  }

  // Epilogue: row m=(b,i), col n=(yo,v) -> out[b][yo][off + v*d + i]
  int yo4[4], v4[4];
#pragma unroll
  for (int n = 0; n < 4; ++n) {
    const int col = n0 + wc * 64 + n * 16 + r15;
    yo4[n] = col / d;
    v4[n] = col - yo4[n] * d;
  }
#pragma unroll
  for (int m = 0; m < 4; ++m)
#pragma unroll
    for (int j = 0; j < 4; ++j) {
      const int row = m0 + wr * 64 + m * 16 + khi * 4 + j;
      const int bb = row / d, i = row - bb * d;
      float* orow = out + (size_t)bb * 36608 + off + i;
#pragma unroll
      for (int n = 0; n < 4; ++n)
        orow[yo4[n] * 286 + v4[n] * d] = acc[m][n][j];
    }
}

// ---------------------------------------------------------------------------
extern "C" void kernel_launch(void* const* d_in, const int* in_sizes, int n_in,
                              void* d_out, int out_size, void* d_ws, size_t ws_size,
                              hipStream_t stream) {
  const float* x  = (const float*)d_in[0];  // (512,128,286)
  const float* w  = (const float*)d_in[1];  // (128,128,512)
  const float* Dm = (const float*)d_in[2];  // (512,286)
  float* out = (float*)d_out;               // (512,128,286)

  // Workspace (bf16 elems): PT 16384*286 ; A 65536*286 ; wb 16384*512 ;
  // DT 384*512.
  __hip_bfloat16* PT = (__hip_bfloat16*)d_ws;
  __hip_bfloat16* A  = PT + 16384 * 286;
  __hip_bfloat16* wb = A + 65536 * 286;
  __hip_bfloat16* DT = wb + 16384 * 512;

  prep_all<<<dim3(7936), dim3(NT), 0, stream>>>(w, Dm, x, wb, DT, A);
  psi_mfma<<<dim3(128, 3), dim3(NT), 0, stream>>>(wb, DT, PT);
  main_gemm<<<dim3(1144), dim3(NT), 0, stream>>>(A, PT, out);
}